// Round 8
// baseline (111.694 us; speedup 1.0000x reference)
//
#include <hip/hip_runtime.h>
#include <math.h>

constexpr int TLEN = 512;
constexpr int CDIM = 64;
constexpr int NBLK = 1024;   // 2 batches * 512 rows / 2 rows per block

// Single fused kernel: 512 blocks x 512 threads (2 blocks/CU, co-resident by
// __launch_bounds__(512,4): 4 waves/EU * 4 EU = 16 waves/CU = 2 x 8-wave blocks).
// Block (b, iA) with iB = 511-iA:
//   1. computes hk,hq for rows iA,iB from its staged x1 (hq stays in LDS,
//      hk written transposed to global hkt4)
//   2. device-scope atomic barrier (all 512 blocks)
//   3. scores for both rows (coalesced hkt4 reads) -> 1-barrier softmax ->
//      shared-load PV -> Wv epilogue.
__global__ __launch_bounds__(512, 4) void fused_kernel(
    const float* __restrict__ x,  const float* __restrict__ pos,
    const float* __restrict__ W1, const float* __restrict__ b1,
    const float* __restrict__ W2, const float* __restrict__ b2,
    const float* __restrict__ Wv, unsigned int* __restrict__ counter,
    float4* __restrict__ hkt4, float* __restrict__ out)
{
    const int tid = threadIdx.x;
    const int idx = blockIdx.x;               // 0..511
    const int b   = idx & 1;
    const int iA  = idx >> 1;                 // 0..255
    const int iB  = (TLEN - 1) - iA;          // 256..511

    __shared__ alignas(16) float x1s[2][128];
    __shared__ float hqp[2][CDIM][4];
    __shared__ float hkp[2][CDIM][4];
    __shared__ alignas(16) float hq_sf[2][CDIM];
    __shared__ alignas(16) float hk_sf[2][CDIM];
    __shared__ float4 w24_s[16];
    __shared__ alignas(16) float pA[TLEN];
    __shared__ alignas(16) float pB[TLEN];
    __shared__ float4 wred4[8];               // per-wave {mA, sumA, mB, sumB}
    __shared__ float pvs[2][8][CDIM];
    __shared__ alignas(16) float o_s[2][CDIM];

    // ---- stage x1 for both rows + W2 ----
    if (tid < 256) {
        const int rp = tid >> 7, d = tid & 127;
        const int i  = rp ? iB : iA;
        const int r  = b * TLEN + i;
        x1s[rp][d] = (d < CDIM) ? pos[i * CDIM + d] : x[r * CDIM + (d - CDIM)];
    } else if (tid < 272) {
        w24_s[tid - 256] = ((const float4*)W2)[tid - 256];
    }
    __syncthreads();

    // ---- hk + hq partials: thread -> (rp, c, part), two 32-MAC dots ----
    {
        const int rp = tid >> 8, c = (tid >> 2) & 63, part = tid & 3;
        const float4* wkp = (const float4*)(W1 + c * 256) + part * 8;  // Wk
        const float4* wqp = wkp + 32;                                   // Wq
        const float4* xv  = ((const float4*)x1s[rp]) + part * 8;
        float4 ak = make_float4(0.f, 0.f, 0.f, 0.f);
        float4 aq = make_float4(0.f, 0.f, 0.f, 0.f);
        #pragma unroll
        for (int d4 = 0; d4 < 8; ++d4) {
            const float4 xx = xv[d4];
            const float4 wk = wkp[d4];
            const float4 wq = wqp[d4];
            ak.x = fmaf(xx.x, wk.x, ak.x); ak.y = fmaf(xx.y, wk.y, ak.y);
            ak.z = fmaf(xx.z, wk.z, ak.z); ak.w = fmaf(xx.w, wk.w, ak.w);
            aq.x = fmaf(xx.x, wq.x, aq.x); aq.y = fmaf(xx.y, wq.y, aq.y);
            aq.z = fmaf(xx.z, wq.z, aq.z); aq.w = fmaf(xx.w, wq.w, aq.w);
        }
        hkp[rp][c][part] = (ak.x + ak.y) + (ak.z + ak.w);
        hqp[rp][c][part] = (aq.x + aq.y) + (aq.z + aq.w);
    }
    __syncthreads();
    if (tid < 128) {
        const int rp = tid >> 6, c = tid & 63;
        hq_sf[rp][c] = hqp[rp][c][0] + hqp[rp][c][1] + hqp[rp][c][2]
                     + hqp[rp][c][3] + b1[c];
        hk_sf[rp][c] = hkp[rp][c][0] + hkp[rp][c][1] + hkp[rp][c][2]
                     + hkp[rp][c][3];
    }
    __syncthreads();
    // write this block's hk rows, transposed: hkt4[(b*16+c4)*512 + t]
    if (tid < 32) {
        const int rp = tid >> 4, c4 = tid & 15;
        const int t  = rp ? iB : iA;
        hkt4[(b * 16 + c4) * TLEN + t] = *(const float4*)&hk_sf[rp][c4 * 4];
    }
    __syncthreads();   // wave0 drains its hkt stores (vmcnt(0) before barrier)

    // ---- device-scope grid barrier (all blocks co-resident) ----
    if (tid == 0) {
        __threadfence();                      // release: L2 writeback
        __hip_atomic_fetch_add(counter, 1u, __ATOMIC_RELEASE,
                               __HIP_MEMORY_SCOPE_AGENT);
        while (__hip_atomic_load(counter, __ATOMIC_ACQUIRE,
                                 __HIP_MEMORY_SCOPE_AGENT) < (unsigned)gridDim.x)
            __builtin_amdgcn_s_sleep(2);
        __threadfence();                      // acquire: invalidate stale lines
    }
    __syncthreads();

    // ---- scores for BOTH rows, shared hkt loads ----
    const float b2v = b2[0];
    const float4* hk4b = hkt4 + b * 16 * TLEN;
    const float4* qA4  = (const float4*)hq_sf[0];
    const float4* qB4  = (const float4*)hq_sf[1];
    const int j = tid;

    float4 aA = make_float4(0.f, 0.f, 0.f, 0.f);
    float4 aB = make_float4(0.f, 0.f, 0.f, 0.f);
    #pragma unroll
    for (int c4 = 0; c4 < 16; ++c4) {
        const float4 kk = hk4b[c4 * TLEN + j];     // 16B/lane, coalesced
        const float4 qa = qA4[c4];
        const float4 qb = qB4[c4];
        const float4 ww = w24_s[c4];
        aA.x = fmaf(fmaxf(kk.x + qa.x, 0.f), ww.x, aA.x);
        aA.y = fmaf(fmaxf(kk.y + qa.y, 0.f), ww.y, aA.y);
        aA.z = fmaf(fmaxf(kk.z + qa.z, 0.f), ww.z, aA.z);
        aA.w = fmaf(fmaxf(kk.w + qa.w, 0.f), ww.w, aA.w);
        aB.x = fmaf(fmaxf(kk.x + qb.x, 0.f), ww.x, aB.x);
        aB.y = fmaf(fmaxf(kk.y + qb.y, 0.f), ww.y, aB.y);
        aB.z = fmaf(fmaxf(kk.z + qb.z, 0.f), ww.z, aB.z);
        aB.w = fmaf(fmaxf(kk.w + qb.w, 0.f), ww.w, aB.w);
    }
    const bool vA = (j <= iA), vB = (j <= iB);
    float sA = vA ? ((aA.x + aA.y) + (aA.z + aA.w) + b2v) * 0.125f : -1e30f;
    float sB = vB ? ((aB.x + aB.y) + (aB.z + aB.w) + b2v) * 0.125f : -1e30f;

    // per-wave softmax stats (shfl only), one barrier to combine
    float mAw = sA, mBw = sB;
    #pragma unroll
    for (int off = 32; off > 0; off >>= 1) {
        mAw = fmaxf(mAw, __shfl_xor(mAw, off));
        mBw = fmaxf(mBw, __shfl_xor(mBw, off));
    }
    const float ptA = vA ? __expf(sA - mAw) : 0.f;
    const float ptB = vB ? __expf(sB - mBw) : 0.f;
    float sAw = ptA, sBw = ptB;
    #pragma unroll
    for (int off = 32; off > 0; off >>= 1) {
        sAw += __shfl_xor(sAw, off);
        sBw += __shfl_xor(sBw, off);
    }
    const int w = tid >> 6;
    if ((tid & 63) == 0) wred4[w] = make_float4(mAw, sAw, mBw, sBw);
    __syncthreads();

    float mA = -1e30f, mB = -1e30f;
    #pragma unroll
    for (int ww = 0; ww < 8; ++ww) {
        const float4 rd = wred4[ww];
        mA = fmaxf(mA, rd.x);
        mB = fmaxf(mB, rd.z);
    }
    float sumA = 0.f, sumB = 0.f;
    #pragma unroll
    for (int ww = 0; ww < 8; ++ww) {
        const float4 rd = wred4[ww];
        sumA = fmaf(rd.y, __expf(rd.x - mA), sumA);
        sumB = fmaf(rd.w, __expf(rd.z - mB), sumB);
    }
    pA[j] = ptA * (__expf(mAw - mA) / sumA);
    pB[j] = ptB * (__expf(mBw - mB) / sumB);
    __syncthreads();

    // ---- PV for BOTH rows, shared x loads ----
    const int h = tid & 63;
    const int g = w;
    const float* xh = x + b * TLEN * CDIM + h;
    const float4* pA4 = (const float4*)pA;
    const float4* pB4 = (const float4*)pB;
    const int nj4 = (iB >> 2) + 1;
    float aA0 = 0.f, aA1 = 0.f, aA2 = 0.f, aA3 = 0.f;
    float aB0 = 0.f, aB1 = 0.f, aB2 = 0.f, aB3 = 0.f;
    for (int j4 = g; j4 < nj4; j4 += 8) {
        const float4 pa = pA4[j4];             // uniform LDS read (broadcast)
        const float4 pb = pB4[j4];
        const int j0 = j4 * 4;
        const float x0 = xh[j0 * CDIM];        // coalesced 256B/wave
        const float x1 = xh[(j0 + 1) * CDIM];
        const float x2 = xh[(j0 + 2) * CDIM];
        const float x3 = xh[(j0 + 3) * CDIM];
        aA0 = fmaf(pa.x, x0, aA0); aB0 = fmaf(pb.x, x0, aB0);
        aA1 = fmaf(pa.y, x1, aA1); aB1 = fmaf(pb.y, x1, aB1);
        aA2 = fmaf(pa.z, x2, aA2); aB2 = fmaf(pb.z, x2, aB2);
        aA3 = fmaf(pa.w, x3, aA3); aB3 = fmaf(pb.w, x3, aB3);
    }
    pvs[0][g][h] = (aA0 + aA1) + (aA2 + aA3);
    pvs[1][g][h] = (aB0 + aB1) + (aB2 + aB3);
    __syncthreads();
    if (tid < 128) {
        const int rp = tid >> 6, hh = tid & 63;
        float o = pvs[rp][0][hh];
        #pragma unroll
        for (int ww = 1; ww < 8; ++ww) o += pvs[rp][ww][hh];
        o_s[rp][hh] = o;
    }
    __syncthreads();
    if (tid < 128) {                          // out[h] = o . Wv[h,:]
        const int rp = tid >> 6, hh = tid & 63;
        const int i  = rp ? iB : iA;
        const float4* wv = (const float4*)(Wv + hh * CDIM);
        const float4* o4 = (const float4*)o_s[rp];
        float4 a = make_float4(0.f, 0.f, 0.f, 0.f);
        #pragma unroll
        for (int c4 = 0; c4 < 16; ++c4) {
            const float4 wwv = wv[c4];
            const float4 oo = o4[c4];
            a.x = fmaf(oo.x, wwv.x, a.x); a.y = fmaf(oo.y, wwv.y, a.y);
            a.z = fmaf(oo.z, wwv.z, a.z); a.w = fmaf(oo.w, wwv.w, a.w);
        }
        out[(b * TLEN + i) * CDIM + hh] = (a.x + a.y) + (a.z + a.w);
    }
}

extern "C" void kernel_launch(void* const* d_in, const int* in_sizes, int n_in,
                              void* d_out, int out_size, void* d_ws, size_t ws_size,
                              hipStream_t stream)
{
    const float* x   = (const float*)d_in[0];
    const float* pos = (const float*)d_in[1];
    const float* W1  = (const float*)d_in[2];
    const float* b1  = (const float*)d_in[3];
    const float* W2  = (const float*)d_in[4];
    const float* b2  = (const float*)d_in[5];
    const float* Wv  = (const float*)d_in[6];
    float* out = (float*)d_out;

    unsigned int* counter = (unsigned int*)d_ws;
    float4* hkt4 = (float4*)((char*)d_ws + 256);   // 256 KiB transposed hk

    hipMemsetAsync(counter, 0, 64, stream);        // reset barrier (capturable)
    fused_kernel<<<NBLK / 2, 512, 0, stream>>>(x, pos, W1, b1, W2, b2, Wv,
                                               counter, hkt4, out);
}

// Round 9
// 25.429 us; speedup vs baseline: 4.3924x; 4.3924x over previous
//
#include <hip/hip_runtime.h>
#include <math.h>

constexpr int TLEN = 512;
constexpr int CDIM = 64;
constexpr int BDIM = 2;

// Phase 1: hkt4[(b*16 + c4)*512 + t] = float4 over c of
// hk[b,t,c] = sum_d x1[b,t,d]*W1[c,d].  256 blocks x 256 threads, 4 rows/block.
__global__ __launch_bounds__(256) void hk_kernel(
    const float* __restrict__ x, const float* __restrict__ pos,
    const float* __restrict__ W1, float4* __restrict__ hkt4)
{
    const int tid = threadIdx.x;
    const int c   = tid & 63;
    const int sub = tid >> 6;                 // 4 rows per block
    const int r0g = blockIdx.x * 4;           // global row base
    const int b   = r0g >> 9;
    const int t0  = r0g & (TLEN - 1);

    __shared__ alignas(16) float x1s[4][128];
    __shared__ float hks[CDIM][4];

    #pragma unroll
    for (int e = tid; e < 4 * 128; e += 256) {
        const int r4 = e >> 7, d = e & 127;
        const int grow = r0g + r4;
        const int tt = grow & (TLEN - 1);
        x1s[r4][d] = (d < CDIM) ? pos[tt * CDIM + d]
                                : x[grow * CDIM + (d - CDIM)];
    }
    __syncthreads();

    const float4* wk = (const float4*)(W1 + c * 256);   // Wk row c
    const float4* xv = (const float4*)x1s[sub];         // broadcast per wave
    float4 a = make_float4(0.f, 0.f, 0.f, 0.f);
    #pragma unroll 8
    for (int d4 = 0; d4 < 32; ++d4) {
        const float4 xx = xv[d4];
        const float4 ww = wk[d4];
        a.x = fmaf(xx.x, ww.x, a.x); a.y = fmaf(xx.y, ww.y, a.y);
        a.z = fmaf(xx.z, ww.z, a.z); a.w = fmaf(xx.w, ww.w, a.w);
    }
    hks[c][sub] = (a.x + a.y) + (a.z + a.w);
    __syncthreads();

    if (tid < 64) {                            // transpose-store, f4 over c
        const int c4 = tid >> 2, tl = tid & 3;
        const float4 v = make_float4(hks[c4 * 4 + 0][tl], hks[c4 * 4 + 1][tl],
                                     hks[c4 * 4 + 2][tl], hks[c4 * 4 + 3][tl]);
        hkt4[(b * 16 + c4) * TLEN + t0 + tl] = v;
    }
}

// Phase 2: one block per 4 rows {p, p+128, 383-p, 511-p} (two balanced pairs,
// 1026 j-units const). hkt/x/Wq loads shared across 4 rows.
__global__ __launch_bounds__(512) void attn_kernel(
    const float* __restrict__ x,  const float* __restrict__ pos,
    const float* __restrict__ W1, const float* __restrict__ b1,
    const float* __restrict__ W2, const float* __restrict__ b2,
    const float* __restrict__ Wv, const float4* __restrict__ hkt4,
    float* __restrict__ out)
{
    const int tid = threadIdx.x;
    const int idx = blockIdx.x;               // 0..255
    const int b   = idx & 1;
    const int p   = idx >> 1;                 // 0..127
    int r[4];
    r[0] = p; r[1] = p + 128; r[2] = 383 - p; r[3] = 511 - p;

    __shared__ alignas(16) float x1s[4][128];
    __shared__ float hqp[4][CDIM][2];
    __shared__ alignas(16) float hq_sf[4][CDIM];
    __shared__ float4 w24_s[16];
    __shared__ alignas(16) float pS[4][TLEN];
    __shared__ float4 wredm[8];                // per-wave row-max (4 rows)
    __shared__ float4 wreds[8];                // per-wave row-sum (4 rows)
    __shared__ float pvs[4][8][CDIM];
    __shared__ alignas(16) float o_s[4][CDIM];

    // ---- stage x1 for 4 rows (+ W2 by first 16 threads) ----
    {
        const int rp = tid >> 7, d = tid & 127;
        const int i  = r[rp];
        x1s[rp][d] = (d < CDIM) ? pos[i * CDIM + d]
                                : x[(b * TLEN + i) * CDIM + (d - CDIM)];
        if (tid < 16) w24_s[tid] = ((const float4*)W2)[tid];
    }
    __syncthreads();

    // ---- hq: thread -> (row k, c, part half) 16-f4 dots ----
    {
        const int k = tid >> 7, c = (tid >> 1) & 63, part = tid & 1;
        const float4* wq = (const float4*)(W1 + c * 256 + 128) + part * 16;
        const float4* xv = ((const float4*)x1s[k]) + part * 16;
        float4 a = make_float4(0.f, 0.f, 0.f, 0.f);
        #pragma unroll
        for (int d4 = 0; d4 < 16; ++d4) {
            const float4 xx = xv[d4];
            const float4 ww = wq[d4];
            a.x = fmaf(xx.x, ww.x, a.x); a.y = fmaf(xx.y, ww.y, a.y);
            a.z = fmaf(xx.z, ww.z, a.z); a.w = fmaf(xx.w, ww.w, a.w);
        }
        hqp[k][c][part] = (a.x + a.y) + (a.z + a.w);
    }
    __syncthreads();
    if (tid < 256) {
        const int k = tid >> 6, c = tid & 63;
        hq_sf[k][c] = hqp[k][c][0] + hqp[k][c][1] + b1[c];
    }
    __syncthreads();

    // ---- scores for 4 rows, shared hkt loads ----
    const float b2v = b2[0];
    const float4* hk4b = hkt4 + b * 16 * TLEN;
    const int j = tid;

    float4 acc0 = make_float4(0.f, 0.f, 0.f, 0.f);
    float4 acc1 = acc0, acc2 = acc0, acc3 = acc0;
    #pragma unroll
    for (int c4 = 0; c4 < 16; ++c4) {
        const float4 kk = hk4b[c4 * TLEN + j];       // 16B/lane coalesced
        const float4 ww = w24_s[c4];
        const float4 q0 = ((const float4*)hq_sf[0])[c4];
        const float4 q1 = ((const float4*)hq_sf[1])[c4];
        const float4 q2 = ((const float4*)hq_sf[2])[c4];
        const float4 q3 = ((const float4*)hq_sf[3])[c4];
        acc0.x = fmaf(fmaxf(kk.x + q0.x, 0.f), ww.x, acc0.x);
        acc0.y = fmaf(fmaxf(kk.y + q0.y, 0.f), ww.y, acc0.y);
        acc0.z = fmaf(fmaxf(kk.z + q0.z, 0.f), ww.z, acc0.z);
        acc0.w = fmaf(fmaxf(kk.w + q0.w, 0.f), ww.w, acc0.w);
        acc1.x = fmaf(fmaxf(kk.x + q1.x, 0.f), ww.x, acc1.x);
        acc1.y = fmaf(fmaxf(kk.y + q1.y, 0.f), ww.y, acc1.y);
        acc1.z = fmaf(fmaxf(kk.z + q1.z, 0.f), ww.z, acc1.z);
        acc1.w = fmaf(fmaxf(kk.w + q1.w, 0.f), ww.w, acc1.w);
        acc2.x = fmaf(fmaxf(kk.x + q2.x, 0.f), ww.x, acc2.x);
        acc2.y = fmaf(fmaxf(kk.y + q2.y, 0.f), ww.y, acc2.y);
        acc2.z = fmaf(fmaxf(kk.z + q2.z, 0.f), ww.z, acc2.z);
        acc2.w = fmaf(fmaxf(kk.w + q2.w, 0.f), ww.w, acc2.w);
        acc3.x = fmaf(fmaxf(kk.x + q3.x, 0.f), ww.x, acc3.x);
        acc3.y = fmaf(fmaxf(kk.y + q3.y, 0.f), ww.y, acc3.y);
        acc3.z = fmaf(fmaxf(kk.z + q3.z, 0.f), ww.z, acc3.z);
        acc3.w = fmaf(fmaxf(kk.w + q3.w, 0.f), ww.w, acc3.w);
    }
    float s[4];
    s[0] = (acc0.x + acc0.y) + (acc0.z + acc0.w);
    s[1] = (acc1.x + acc1.y) + (acc1.z + acc1.w);
    s[2] = (acc2.x + acc2.y) + (acc2.z + acc2.w);
    s[3] = (acc3.x + acc3.y) + (acc3.z + acc3.w);
    bool valid[4];
    float mw[4], pt[4], sw[4];
    #pragma unroll
    for (int k = 0; k < 4; ++k) {
        valid[k] = (j <= r[k]);
        s[k] = valid[k] ? (s[k] + b2v) * 0.125f : -1e30f;
        float m = s[k];
        #pragma unroll
        for (int off = 32; off > 0; off >>= 1)
            m = fmaxf(m, __shfl_xor(m, off));
        mw[k] = m;
        pt[k] = valid[k] ? __expf(s[k] - m) : 0.f;
        float sm = pt[k];
        #pragma unroll
        for (int off = 32; off > 0; off >>= 1)
            sm += __shfl_xor(sm, off);
        sw[k] = sm;
    }
    const int w = tid >> 6;
    if ((tid & 63) == 0) {
        wredm[w] = make_float4(mw[0], mw[1], mw[2], mw[3]);
        wreds[w] = make_float4(sw[0], sw[1], sw[2], sw[3]);
    }
    __syncthreads();

    float4 gm = wredm[0];
    #pragma unroll
    for (int ww = 1; ww < 8; ++ww) {
        const float4 rm = wredm[ww];
        gm.x = fmaxf(gm.x, rm.x); gm.y = fmaxf(gm.y, rm.y);
        gm.z = fmaxf(gm.z, rm.z); gm.w = fmaxf(gm.w, rm.w);
    }
    float4 gs = make_float4(0.f, 0.f, 0.f, 0.f);
    #pragma unroll
    for (int ww = 0; ww < 8; ++ww) {
        const float4 rm = wredm[ww];
        const float4 rs = wreds[ww];
        gs.x = fmaf(rs.x, __expf(rm.x - gm.x), gs.x);
        gs.y = fmaf(rs.y, __expf(rm.y - gm.y), gs.y);
        gs.z = fmaf(rs.z, __expf(rm.z - gm.z), gs.z);
        gs.w = fmaf(rs.w, __expf(rm.w - gm.w), gs.w);
    }
    const float* gmp = (const float*)&gm;
    const float* gsp = (const float*)&gs;
    #pragma unroll
    for (int k = 0; k < 4; ++k)
        pS[k][j] = pt[k] * (__expf(mw[k] - gmp[k]) / gsp[k]);
    __syncthreads();

    // ---- PV for 4 rows, shared x loads ----
    const int h = tid & 63;
    const int g = w;
    const float* xh = x + b * TLEN * CDIM + h;
    const int nj4 = (r[3] >> 2) + 1;           // r[3] is the max row
    float4 a0 = make_float4(0.f, 0.f, 0.f, 0.f);
    float4 a1 = a0, a2 = a0, a3 = a0;
    for (int j4 = g; j4 < nj4; j4 += 8) {
        const float4 p0 = ((const float4*)pS[0])[j4];   // LDS broadcast
        const float4 p1 = ((const float4*)pS[1])[j4];
        const float4 p2 = ((const float4*)pS[2])[j4];
        const float4 p3 = ((const float4*)pS[3])[j4];
        const int j0 = j4 * 4;
        const float x0 = xh[j0 * CDIM];                 // coalesced
        const float x1 = xh[(j0 + 1) * CDIM];
        const float x2 = xh[(j0 + 2) * CDIM];
        const float x3 = xh[(j0 + 3) * CDIM];
        a0.x = fmaf(p0.x, x0, a0.x); a0.y = fmaf(p0.y, x1, a0.y);
        a0.z = fmaf(p0.z, x2, a0.z); a0.w = fmaf(p0.w, x3, a0.w);
        a1.x = fmaf(p1.x, x0, a1.x); a1.y = fmaf(p1.y, x1, a1.y);
        a1.z = fmaf(p1.z, x2, a1.z); a1.w = fmaf(p1.w, x3, a1.w);
        a2.x = fmaf(p2.x, x0, a2.x); a2.y = fmaf(p2.y, x1, a2.y);
        a2.z = fmaf(p2.z, x2, a2.z); a2.w = fmaf(p2.w, x3, a2.w);
        a3.x = fmaf(p3.x, x0, a3.x); a3.y = fmaf(p3.y, x1, a3.y);
        a3.z = fmaf(p3.z, x2, a3.z); a3.w = fmaf(p3.w, x3, a3.w);
    }
    pvs[0][g][h] = (a0.x + a0.y) + (a0.z + a0.w);
    pvs[1][g][h] = (a1.x + a1.y) + (a1.z + a1.w);
    pvs[2][g][h] = (a2.x + a2.y) + (a2.z + a2.w);
    pvs[3][g][h] = (a3.x + a3.y) + (a3.z + a3.w);
    __syncthreads();
    if (tid < 256) {
        const int k = tid >> 6, hh = tid & 63;
        float o = pvs[k][0][hh];
        #pragma unroll
        for (int ww = 1; ww < 8; ++ww) o += pvs[k][ww][hh];
        o_s[k][hh] = o;
    }
    __syncthreads();
    if (tid < 256) {                           // out[h] = o_k . Wv[h,:]
        const int k = tid >> 6, hh = tid & 63;
        const float4* wv = (const float4*)(Wv + hh * CDIM);
        const float4* o4 = (const float4*)o_s[k];
        float4 a = make_float4(0.f, 0.f, 0.f, 0.f);
        #pragma unroll
        for (int c4 = 0; c4 < 16; ++c4) {
            const float4 wwv = wv[c4];
            const float4 oo = o4[c4];
            a.x = fmaf(oo.x, wwv.x, a.x); a.y = fmaf(oo.y, wwv.y, a.y);
            a.z = fmaf(oo.z, wwv.z, a.z); a.w = fmaf(oo.w, wwv.w, a.w);
        }
        out[(b * TLEN + r[k]) * CDIM + hh] = (a.x + a.y) + (a.z + a.w);
    }
}

extern "C" void kernel_launch(void* const* d_in, const int* in_sizes, int n_in,
                              void* d_out, int out_size, void* d_ws, size_t ws_size,
                              hipStream_t stream)
{
    const float* x   = (const float*)d_in[0];
    const float* pos = (const float*)d_in[1];
    const float* W1  = (const float*)d_in[2];
    const float* b1  = (const float*)d_in[3];
    const float* W2  = (const float*)d_in[4];
    const float* b2  = (const float*)d_in[5];
    const float* Wv  = (const float*)d_in[6];
    float* out = (float*)d_out;

    float4* hkt4 = (float4*)d_ws;              // 256 KiB transposed hk

    hk_kernel<<<BDIM * TLEN / 4, 256, 0, stream>>>(x, pos, W1, hkt4);
    attn_kernel<<<BDIM * TLEN / 4, 512, 0, stream>>>(x, pos, W1, b1, W2, b2, Wv,
                                                     hkt4, out);
}

// Round 10
// 21.152 us; speedup vs baseline: 5.2806x; 1.2022x over previous
//
#include <hip/hip_runtime.h>
#include <math.h>

constexpr int TLEN = 512;
constexpr int CDIM = 64;
constexpr int BDIM = 2;

// Phase 1: hkt4[(b*16+c4)*512 + t] = float4-over-c of hk[b,t,c].
// 128 blocks x 512 threads, 8 rows/block. Wk staged in LDS (coalesced +
// XOR-swizzled) so the per-lane row reads are conflict-free LDS instead of
// 64-line L1/L2 fan-out.
__global__ __launch_bounds__(512) void hk_kernel(
    const float* __restrict__ x, const float* __restrict__ pos,
    const float* __restrict__ W1, float4* __restrict__ hkt4)
{
    const int tid = threadIdx.x;
    const int r0g = blockIdx.x * 8;           // global row base (b*512+t)
    const int b   = r0g >> 9;
    const int t0  = r0g & (TLEN - 1);

    __shared__ float4 wk_s[64 * 32];          // 32 KiB, swizzled
    __shared__ alignas(16) float x1s[8][128];
    __shared__ float hks[CDIM][9];            // +1 pad

    const float4* W1f4 = (const float4*)W1;   // 64 f4 per row
    #pragma unroll
    for (int m = tid; m < 64 * 32; m += 512) {
        const int c = m >> 5, e4 = m & 31;
        wk_s[c * 32 + (e4 ^ (c & 31))] = W1f4[c * 64 + e4];   // Wk = f4 0..31
    }
    #pragma unroll
    for (int e = tid; e < 8 * 128; e += 512) {
        const int r4 = e >> 7, d = e & 127;
        const int grow = r0g + r4;
        const int tt = grow & (TLEN - 1);
        x1s[r4][d] = (d < CDIM) ? pos[tt * CDIM + d]
                                : x[grow * CDIM + (d - CDIM)];
    }
    __syncthreads();

    {   // one dot per thread: (sub, c)
        const int sub = tid >> 6, c = tid & 63;
        const float4* xv = (const float4*)x1s[sub];      // broadcast
        const float4* wb = wk_s + c * 32;
        const int sw = c & 31;
        float4 a = make_float4(0.f, 0.f, 0.f, 0.f);
        #pragma unroll
        for (int d4 = 0; d4 < 32; ++d4) {
            const float4 xx = xv[d4];
            const float4 ww = wb[d4 ^ sw];               // conflict-free
            a.x = fmaf(xx.x, ww.x, a.x); a.y = fmaf(xx.y, ww.y, a.y);
            a.z = fmaf(xx.z, ww.z, a.z); a.w = fmaf(xx.w, ww.w, a.w);
        }
        hks[c][sub] = (a.x + a.y) + (a.z + a.w);
    }
    __syncthreads();

    if (tid < 128) {                           // transpose-store f4 over c
        const int c4 = tid >> 3, tl = tid & 7;
        const float4 v = make_float4(hks[c4 * 4 + 0][tl], hks[c4 * 4 + 1][tl],
                                     hks[c4 * 4 + 2][tl], hks[c4 * 4 + 3][tl]);
        hkt4[(b * 16 + c4) * TLEN + t0 + tl] = v;
    }
}

// Phase 2: one block per 4 rows {p, p+128, 383-p, 511-p} (1026 j-units const).
// Wq and Wv staged in LDS (coalesced + swizzled); score/softmax/PV as R9.
__global__ __launch_bounds__(512) void attn_kernel(
    const float* __restrict__ x,  const float* __restrict__ pos,
    const float* __restrict__ W1, const float* __restrict__ b1,
    const float* __restrict__ W2, const float* __restrict__ b2,
    const float* __restrict__ Wv, const float4* __restrict__ hkt4,
    float* __restrict__ out)
{
    const int tid = threadIdx.x;
    const int idx = blockIdx.x;               // 0..255
    const int b   = idx & 1;
    const int p   = idx >> 1;                 // 0..127
    int r[4];
    r[0] = p; r[1] = p + 128; r[2] = 383 - p; r[3] = 511 - p;

    __shared__ float4 wq_s[64 * 32];          // 32 KiB swizzled Wq
    __shared__ float4 wv_s[64 * 16];          // 16 KiB swizzled Wv
    __shared__ alignas(16) float x1s[4][128];
    __shared__ float hqp[4][CDIM][2];
    __shared__ alignas(16) float hq_sf[4][CDIM];
    __shared__ float4 w24_s[16];
    __shared__ alignas(16) float pS[4][TLEN];
    __shared__ float4 wredm[8];
    __shared__ float4 wreds[8];
    __shared__ float pvs[4][8][CDIM];
    __shared__ alignas(16) float o_s[4][CDIM];

    // ---- stage Wq, Wv (coalesced, swizzled), x1 for 4 rows, W2 ----
    const float4* W1f4 = (const float4*)W1;
    #pragma unroll
    for (int m = tid; m < 64 * 32; m += 512) {
        const int c = m >> 5, e4 = m & 31;
        wq_s[c * 32 + (e4 ^ (c & 31))] = W1f4[c * 64 + 32 + e4];  // Wq f4 32..63
    }
    const float4* Wvf4 = (const float4*)Wv;
    #pragma unroll
    for (int m = tid; m < 64 * 16; m += 512) {
        const int hh = m >> 4, e4 = m & 15;
        wv_s[hh * 16 + (e4 ^ (hh & 15))] = Wvf4[hh * 16 + e4];
    }
    {
        const int rp = tid >> 7, d = tid & 127;
        const int i  = r[rp];
        x1s[rp][d] = (d < CDIM) ? pos[i * CDIM + d]
                                : x[(b * TLEN + i) * CDIM + (d - CDIM)];
        if (tid < 16) w24_s[tid] = ((const float4*)W2)[tid];
    }
    __syncthreads();

    // ---- hq: thread -> (row k, half, c); Wq from LDS conflict-free ----
    {
        const int k = tid >> 7, part = (tid >> 6) & 1, c = tid & 63;
        const float4* xv = ((const float4*)x1s[k]) + part * 16;
        const float4* wb = wq_s + c * 32;
        const int sw = c & 31;
        float4 a = make_float4(0.f, 0.f, 0.f, 0.f);
        #pragma unroll
        for (int d4 = 0; d4 < 16; ++d4) {
            const float4 xx = xv[d4];
            const float4 ww = wb[(part * 16 + d4) ^ sw];
            a.x = fmaf(xx.x, ww.x, a.x); a.y = fmaf(xx.y, ww.y, a.y);
            a.z = fmaf(xx.z, ww.z, a.z); a.w = fmaf(xx.w, ww.w, a.w);
        }
        hqp[k][c][part] = (a.x + a.y) + (a.z + a.w);
    }
    __syncthreads();
    if (tid < 256) {
        const int k = tid >> 6, c = tid & 63;
        hq_sf[k][c] = hqp[k][c][0] + hqp[k][c][1] + b1[c];
    }
    __syncthreads();

    // ---- scores for 4 rows, shared coalesced hkt loads (as R9) ----
    const float b2v = b2[0];
    const float4* hk4b = hkt4 + b * 16 * TLEN;
    const int j = tid;

    float4 acc0 = make_float4(0.f, 0.f, 0.f, 0.f);
    float4 acc1 = acc0, acc2 = acc0, acc3 = acc0;
    #pragma unroll
    for (int c4 = 0; c4 < 16; ++c4) {
        const float4 kk = hk4b[c4 * TLEN + j];
        const float4 ww = w24_s[c4];
        const float4 q0 = ((const float4*)hq_sf[0])[c4];
        const float4 q1 = ((const float4*)hq_sf[1])[c4];
        const float4 q2 = ((const float4*)hq_sf[2])[c4];
        const float4 q3 = ((const float4*)hq_sf[3])[c4];
        acc0.x = fmaf(fmaxf(kk.x + q0.x, 0.f), ww.x, acc0.x);
        acc0.y = fmaf(fmaxf(kk.y + q0.y, 0.f), ww.y, acc0.y);
        acc0.z = fmaf(fmaxf(kk.z + q0.z, 0.f), ww.z, acc0.z);
        acc0.w = fmaf(fmaxf(kk.w + q0.w, 0.f), ww.w, acc0.w);
        acc1.x = fmaf(fmaxf(kk.x + q1.x, 0.f), ww.x, acc1.x);
        acc1.y = fmaf(fmaxf(kk.y + q1.y, 0.f), ww.y, acc1.y);
        acc1.z = fmaf(fmaxf(kk.z + q1.z, 0.f), ww.z, acc1.z);
        acc1.w = fmaf(fmaxf(kk.w + q1.w, 0.f), ww.w, acc1.w);
        acc2.x = fmaf(fmaxf(kk.x + q2.x, 0.f), ww.x, acc2.x);
        acc2.y = fmaf(fmaxf(kk.y + q2.y, 0.f), ww.y, acc2.y);
        acc2.z = fmaf(fmaxf(kk.z + q2.z, 0.f), ww.z, acc2.z);
        acc2.w = fmaf(fmaxf(kk.w + q2.w, 0.f), ww.w, acc2.w);
        acc3.x = fmaf(fmaxf(kk.x + q3.x, 0.f), ww.x, acc3.x);
        acc3.y = fmaf(fmaxf(kk.y + q3.y, 0.f), ww.y, acc3.y);
        acc3.z = fmaf(fmaxf(kk.z + q3.z, 0.f), ww.z, acc3.z);
        acc3.w = fmaf(fmaxf(kk.w + q3.w, 0.f), ww.w, acc3.w);
    }
    float s[4];
    s[0] = (acc0.x + acc0.y) + (acc0.z + acc0.w);
    s[1] = (acc1.x + acc1.y) + (acc1.z + acc1.w);
    s[2] = (acc2.x + acc2.y) + (acc2.z + acc2.w);
    s[3] = (acc3.x + acc3.y) + (acc3.z + acc3.w);
    bool valid[4];
    float mw[4], pt[4], sw2[4];
    #pragma unroll
    for (int k = 0; k < 4; ++k) {
        valid[k] = (j <= r[k]);
        s[k] = valid[k] ? (s[k] + b2v) * 0.125f : -1e30f;
        float m = s[k];
        #pragma unroll
        for (int off = 32; off > 0; off >>= 1)
            m = fmaxf(m, __shfl_xor(m, off));
        mw[k] = m;
        pt[k] = valid[k] ? __expf(s[k] - m) : 0.f;
        float sm = pt[k];
        #pragma unroll
        for (int off = 32; off > 0; off >>= 1)
            sm += __shfl_xor(sm, off);
        sw2[k] = sm;
    }
    const int w = tid >> 6;
    if ((tid & 63) == 0) {
        wredm[w] = make_float4(mw[0], mw[1], mw[2], mw[3]);
        wreds[w] = make_float4(sw2[0], sw2[1], sw2[2], sw2[3]);
    }
    __syncthreads();

    float4 gm = wredm[0];
    #pragma unroll
    for (int ww = 1; ww < 8; ++ww) {
        const float4 rm = wredm[ww];
        gm.x = fmaxf(gm.x, rm.x); gm.y = fmaxf(gm.y, rm.y);
        gm.z = fmaxf(gm.z, rm.z); gm.w = fmaxf(gm.w, rm.w);
    }
    float4 gs = make_float4(0.f, 0.f, 0.f, 0.f);
    #pragma unroll
    for (int ww = 0; ww < 8; ++ww) {
        const float4 rm = wredm[ww];
        const float4 rs = wreds[ww];
        gs.x = fmaf(rs.x, __expf(rm.x - gm.x), gs.x);
        gs.y = fmaf(rs.y, __expf(rm.y - gm.y), gs.y);
        gs.z = fmaf(rs.z, __expf(rm.z - gm.z), gs.z);
        gs.w = fmaf(rs.w, __expf(rm.w - gm.w), gs.w);
    }
    const float* gmp = (const float*)&gm;
    const float* gsp = (const float*)&gs;
    #pragma unroll
    for (int k = 0; k < 4; ++k)
        pS[k][j] = pt[k] * (__expf(mw[k] - gmp[k]) / gsp[k]);
    __syncthreads();

    // ---- PV for 4 rows, shared x loads (as R9) ----
    const int h = tid & 63;
    const int g = w;
    const float* xh = x + b * TLEN * CDIM + h;
    const int nj4 = (r[3] >> 2) + 1;
    float4 a0 = make_float4(0.f, 0.f, 0.f, 0.f);
    float4 a1 = a0, a2 = a0, a3 = a0;
    for (int j4 = g; j4 < nj4; j4 += 8) {
        const float4 p0 = ((const float4*)pS[0])[j4];
        const float4 p1 = ((const float4*)pS[1])[j4];
        const float4 p2 = ((const float4*)pS[2])[j4];
        const float4 p3 = ((const float4*)pS[3])[j4];
        const int j0 = j4 * 4;
        const float x0 = xh[j0 * CDIM];
        const float x1 = xh[(j0 + 1) * CDIM];
        const float x2 = xh[(j0 + 2) * CDIM];
        const float x3 = xh[(j0 + 3) * CDIM];
        a0.x = fmaf(p0.x, x0, a0.x); a0.y = fmaf(p0.y, x1, a0.y);
        a0.z = fmaf(p0.z, x2, a0.z); a0.w = fmaf(p0.w, x3, a0.w);
        a1.x = fmaf(p1.x, x0, a1.x); a1.y = fmaf(p1.y, x1, a1.y);
        a1.z = fmaf(p1.z, x2, a1.z); a1.w = fmaf(p1.w, x3, a1.w);
        a2.x = fmaf(p2.x, x0, a2.x); a2.y = fmaf(p2.y, x1, a2.y);
        a2.z = fmaf(p2.z, x2, a2.z); a2.w = fmaf(p2.w, x3, a2.w);
        a3.x = fmaf(p3.x, x0, a3.x); a3.y = fmaf(p3.y, x1, a3.y);
        a3.z = fmaf(p3.z, x2, a3.z); a3.w = fmaf(p3.w, x3, a3.w);
    }
    pvs[0][g][h] = (a0.x + a0.y) + (a0.z + a0.w);
    pvs[1][g][h] = (a1.x + a1.y) + (a1.z + a1.w);
    pvs[2][g][h] = (a2.x + a2.y) + (a2.z + a2.w);
    pvs[3][g][h] = (a3.x + a3.y) + (a3.z + a3.w);
    __syncthreads();
    if (tid < 256) {
        const int k = tid >> 6, hh = tid & 63;
        float o = pvs[k][0][hh];
        #pragma unroll
        for (int ww = 1; ww < 8; ++ww) o += pvs[k][ww][hh];
        o_s[k][hh] = o;
    }
    __syncthreads();
    if (tid < 256) {                           // out = o_k . Wv[h,:], Wv from LDS
        const int k = tid >> 6, hh = tid & 63;
        const float4* wb = wv_s + hh * 16;
        const int sw = hh & 15;
        const float4* o4 = (const float4*)o_s[k];
        float4 a = make_float4(0.f, 0.f, 0.f, 0.f);
        #pragma unroll
        for (int c4 = 0; c4 < 16; ++c4) {
            const float4 wwv = wb[c4 ^ sw];
            const float4 oo = o4[c4];
            a.x = fmaf(oo.x, wwv.x, a.x); a.y = fmaf(oo.y, wwv.y, a.y);
            a.z = fmaf(oo.z, wwv.z, a.z); a.w = fmaf(oo.w, wwv.w, a.w);
        }
        out[(b * TLEN + r[k]) * CDIM + hh] = (a.x + a.y) + (a.z + a.w);
    }
}

extern "C" void kernel_launch(void* const* d_in, const int* in_sizes, int n_in,
                              void* d_out, int out_size, void* d_ws, size_t ws_size,
                              hipStream_t stream)
{
    const float* x   = (const float*)d_in[0];
    const float* pos = (const float*)d_in[1];
    const float* W1  = (const float*)d_in[2];
    const float* b1  = (const float*)d_in[3];
    const float* W2  = (const float*)d_in[4];
    const float* b2  = (const float*)d_in[5];
    const float* Wv  = (const float*)d_in[6];
    float* out = (float*)d_out;

    float4* hkt4 = (float4*)d_ws;              // 256 KiB transposed hk

    hk_kernel<<<BDIM * TLEN / 8, 512, 0, stream>>>(x, pos, W1, hkt4);
    attn_kernel<<<BDIM * TLEN / 4, 512, 0, stream>>>(x, pos, W1, b1, W2, b2, Wv,
                                                     hkt4, out);
}